// Round 6
// baseline (463.473 us; speedup 1.0000x reference)
//
#include <hip/hip_runtime.h>
#include <math.h>

#define KK 128
#define EE 4096
#define MM 512
#define CP 32   // max nnz per q_kn row (c<=32 verified: absmax exactly 0 in prior rounds)

// ws float-offset layout:
#define OFF_U    0              // u[128] (current state; u0 published by k_fused0 blk(0,0))
#define OFF_PA   128            // partials A [128][16]
#define OFF_PB   2176           // partials B [128][16]
#define OFF_CNT  4224           // int cnt[E]
#define OFF_IDXT 41088          // signed char idxT[CP][E] (i-major, sentinel -1), 32768 floats
#define OFF_PE   73856          // P01, a2, scv, invd, bz  (5 x E floats)
#define OFF_BC   1142912        // Bc[k][i][e] compacted B (64 MB)

// NOTE (r2/r3 lesson, recorded): in-kernel grid barriers on MI355X cost
// ~150-350us each here (per-block-leader device-scope fences -> L2
// writeback/invalidate storms across 8 non-coherent XCD L2s). Dispatch
// boundaries do the same sync for ~5-10us. Multi-dispatch is the right
// structure; the only safe fusion is same-block producer->consumer (or
// redundant per-block recompute, used here to absorb the old k_setup).

// K1 (fused): per-block setup + B-compaction + phase 0, one dispatch.
// Block (ec 0..15, k 0..127):
//   - builds support lists for its 256 e's in LDS from q_kn (redundant across k,
//     but q_kn is L2-resident; k==0 blocks publish cnt/idxT/PE to ws for later
//     dispatches -- consumed only across the dispatch boundary, which is safe)
//   - compacts exactly the 4 B-units (k, e0=ec*256+t*64) its phase-0 slice reads
//   - runs phase 0 (identical arithmetic to the old k_phase p==0)
__global__ __launch_bounds__(256) void k_fused0(
    const float* __restrict__ B, const float* __restrict__ U,
    const float* __restrict__ W, const float* __restrict__ beiTa_1,
    const float* __restrict__ beiTa_2, const float* __restrict__ guess_slip,
    const float* __restrict__ A_emb, const float* __restrict__ gamma_c,
    const float* __restrict__ score, const float* __restrict__ ukc,
    const float* __restrict__ q_kn, const float* __restrict__ d,
    const int* __restrict__ stu_id, float* __restrict__ ws,
    float* __restrict__ pout)
{
    __shared__ float lds[64 * KK];           // 32 KB staging; reused as lu/sdv/wred
    __shared__ signed char lidxT[CP][256];   // 8 KB  -> 40960 B total = 4 blocks/CU
    int tid = threadIdx.x;
    int ec = blockIdx.x;   // 0..15
    int k  = blockIdx.y;   // 0..127
    int e  = ec * 256 + tid;

    // ---- support-list build (thread = e), sentinel -1 ----
    #pragma unroll
    for (int i = 0; i < CP; i++) lidxT[i][tid] = -1;
    const float4* qrow = (const float4*)(q_kn + (size_t)e * KK);
    int c = 0;
    for (int j4 = 0; j4 < KK / 4; j4++) {
        float4 q = qrow[j4];
        int j = j4 * 4;
        if (q.x > 0.5f) { if (c < CP) lidxT[c][tid] = (signed char)j;     c++; }
        if (q.y > 0.5f) { if (c < CP) lidxT[c][tid] = (signed char)(j+1); c++; }
        if (q.z > 0.5f) { if (c < CP) lidxT[c][tid] = (signed char)(j+2); c++; }
        if (q.w > 0.5f) { if (c < CP) lidxT[c][tid] = (signed char)(j+3); c++; }
    }
    c = (c < CP) ? c : CP;

    // per-e constants in registers (same arithmetic as old k_setup)
    float id_ = 1.0f / d[e];
    float scr = score[e];
    float p01 = A_emb[3*e] * (1.0f - guess_slip[2*e]) +
                A_emb[3*e+1] * (1.0f - guess_slip[2*e+1]);
    float a2v = A_emb[3*e+2];
    float zc  = 1.0f / (1.0f + __expf(gamma_c[e] * id_ * (scr - 0.5f))) - 0.5f;
    float bzr = beiTa_2[e] * zc;

    // k==0 blocks publish shared copies for p1/p2/final (cross-dispatch only)
    if (k == 0) {
        ((int*)(ws + OFF_CNT))[e] = c;
        signed char* idxT = (signed char*)(ws + OFF_IDXT);
        for (int i = 0; i < CP; i++) idxT[(size_t)i * EE + e] = lidxT[i][tid];
        float* pe = ws + OFF_PE;
        pe[e] = p01; pe[EE + e] = a2v; pe[2*EE + e] = scr;
        pe[3*EE + e] = id_; pe[4*EE + e] = bzr;
    }
    __syncthreads();   // lidxT visible block-wide

    // ---- compact my 4 units (k, e0 in [ec*256, ec*256+256)) ----
    float* Bc = ws + OFF_BC;
    for (int t4 = 0; t4 < 4; t4++) {
        int e0 = ec * 256 + t4 * 64;
        const float4* src = (const float4*)(B + ((size_t)k * EE + e0) * KK);
        float4* dst4 = (float4*)lds;
        #pragma unroll
        for (int it = 0; it < 8; it++)
            dst4[it * 256 + tid] = src[it * 256 + tid];
        __syncthreads();
        int eo = tid & 63;
        int el = t4 * 64 + eo;
        float* BcB = Bc + (size_t)k * CP * EE + e0 + eo;
        for (int i = tid >> 6; i < CP; i += 4) {
            int j = lidxT[i][el];
            unsigned long long m = __ballot(j >= 0);
            if (!m) break;
            if (j >= 0) BcB[(size_t)i * EE] = lds[eo * KK + j];
        }
        __syncthreads();
    }

    // ---- phase 0 (identical arithmetic to old k_phase p==0) ----
    float* lu   = lds;         // [128]
    float* sdv  = lds + 128;   // [128]
    float* wred = lds + 256;   // [4]
    if (tid < KK) {
        float uv = U[(size_t)stu_id[0] * KK + tid];
        lu[tid] = uv;
        float t = uv - 0.5f;
        sdv[tid] = (fabsf(t) > 0.05f) ? t : 0.0f;
        if (ec == 0 && k == 0) ws[tid] = uv;   // u0 for p1's diff bookkeeping
    }
    __syncthreads();

    const float* bp = Bc + (size_t)k * CP * EE + e;
    float su = 0.0f, gs = 0.0f;
    for (int i = 0; i < c; i++) {
        int j   = lidxT[i][tid];
        float b = bp[(size_t)i * EE];
        su += lu[j];
        gs = fmaf(b, (j != k) ? sdv[j] : 0.0f, gs);   // diag term cancels exactly
    }
    float t0 = scr - su * id_;
    float yc = __expf(-t0 * t0);
    float Ic = 1.0f / (1.0f + __expf(p01 + a2v * yc));
    float Gkc = 1.0f / (1.0f + __expf(gs)) - 1.0f;
    size_t o = (size_t)k * EE + e;
    float uw = ukc[o] * W[o];
    float g  = uw * beiTa_1[o];     // == old gW[o] bit-exactly
    float v  = Ic * (g * Gkc + uw * bzr);   // same expression tree as before

    #pragma unroll
    for (int m = 1; m < 64; m <<= 1) v += __shfl_xor(v, m);
    if ((tid & 63) == 0) wred[tid >> 6] = v;
    __syncthreads();
    if (tid == 0) pout[k * 16 + ec] = wred[0] + wred[1] + wred[2] + wred[3];
}

// K2: one model iteration (phase 1/2). Block = (e-chunk 256, k).
// gW/hW are computed on the fly from ukc/W/beiTa_1 (L3-resident, bit-identical).
__global__ __launch_bounds__(256) void k_phase(
    float* __restrict__ ws, float* __restrict__ out,
    const float* __restrict__ pin, float* __restrict__ pout,
    const float* __restrict__ ukc, const float* __restrict__ W,
    const float* __restrict__ beiTa_1, int phase)
{
    __shared__ float lu[KK];
    __shared__ float sdv[KK];
    __shared__ float red2[KK];
    __shared__ float wred[4];
    int tid = threadIdx.x;
    int ec = blockIdx.x;   // 0..15
    int k  = blockIdx.y;   // 0..127
    int e  = ec * 256 + tid;

    if (tid < KK) {
        float s = 0.0f;
        const float* p = pin + tid * 16;
        #pragma unroll
        for (int t = 0; t < 16; t++) s += p[t];
        float uv = 1.0f / (1.0f + __expf(s));
        lu[tid] = uv;
        float t = uv - 0.5f;
        sdv[tid] = (fabsf(t) > 0.05f) ? t : 0.0f;
    }
    __syncthreads();

    const int* cnt = (const int*)(ws + OFF_CNT);
    const signed char* idxT = (const signed char*)(ws + OFF_IDXT);
    const float* P01  = ws + OFF_PE;
    const float* a2   = P01 + EE;
    const float* scv  = a2 + EE;
    const float* invd = scv + EE;
    const float* bzv  = invd + EE;
    const float* Bc   = ws + OFF_BC;

    int c = cnt[e];
    const signed char* it = idxT + e;
    const float* bp = Bc + (size_t)k * CP * EE + e;
    float su = 0.0f, gs = 0.0f;
    for (int i = 0; i < c; i++) {
        int j   = it[(size_t)i * EE];
        float b = bp[(size_t)i * EE];
        su += lu[j];
        gs = fmaf(b, (j != k) ? sdv[j] : 0.0f, gs);   // diag term cancels exactly
    }
    float t0 = scv[e] - su * invd[e];
    float yc = __expf(-t0 * t0);
    float Ic = 1.0f / (1.0f + __expf(P01[e] + a2[e] * yc));
    float Gkc = 1.0f / (1.0f + __expf(gs)) - 1.0f;
    size_t o = (size_t)k * EE + e;
    float uw = ukc[o] * W[o];
    float g  = uw * beiTa_1[o];
    float v  = Ic * (g * Gkc + uw * bzv[e]);

    #pragma unroll
    for (int m = 1; m < 64; m <<= 1) v += __shfl_xor(v, m);
    if ((tid & 63) == 0) wred[tid >> 6] = v;
    __syncthreads();
    if (tid == 0) pout[k * 16 + ec] = wred[0] + wred[1] + wred[2] + wred[3];

    // bookkeeping: diff norm of previous update, advance ws-u, state_2nd_last
    if (blockIdx.x == 0 && blockIdx.y == 0) {
        if (tid < KK) {
            float dd = lu[tid] - ws[tid];
            red2[tid] = dd * dd;
        }
        __syncthreads();
        for (int s2 = 64; s2 > 0; s2 >>= 1) {
            if (tid < s2) red2[tid] += red2[tid + s2];
            __syncthreads();
        }
        if (tid == 0) out[768 + (phase - 1)] = sqrtf(red2[0]);
        if (tid < KK) {
            ws[tid] = lu[tid];
            if (phase == 2) out[128 + tid] = lu[tid];   // state_2nd_last
        }
    }
}

// K3: final update + diff + state_last + predict (M=512); uses idxT
__global__ __launch_bounds__(512) void k_final(
    float* __restrict__ ws, float* __restrict__ out, const float* __restrict__ pin,
    const int* __restrict__ ex_id, const float* __restrict__ alpha,
    const float* __restrict__ gamma_e)
{
    __shared__ float un_s[KK];
    __shared__ float red[KK];
    int tid = threadIdx.x;
    if (tid < KK) {
        float s = 0.0f;
        const float* p = pin + tid * 16;
        #pragma unroll
        for (int t = 0; t < 16; t++) s += p[t];
        float un = 1.0f / (1.0f + __expf(s));
        float dd = un - ws[tid];
        red[tid] = dd * dd;
        un_s[tid] = un;
        out[tid] = un;   // state_last
    }
    __syncthreads();
    for (int s2 = 64; s2 > 0; s2 >>= 1) {
        if (tid < s2) red[tid] += red[tid + s2];
        __syncthreads();
    }
    if (tid == 0) out[770] = sqrtf(red[0]);

    const int* cnt = (const int*)(ws + OFF_CNT);
    const signed char* idxT = (const signed char*)(ws + OFF_IDXT);
    const float* invd = ws + OFF_PE + 3 * EE;
    int e = ex_id[tid];
    int c = cnt[e];
    float su = 0.0f;
    for (int i = 0; i < c; i++) su += un_s[idxT[(size_t)i * EE + e]];
    float Ukse = su * invd[e] - 0.5f;
    out[256 + tid] = 1.0f / (1.0f + __expf(alpha[e] * Ukse + gamma_e[e]));
}

extern "C" void kernel_launch(void* const* d_in, const int* in_sizes, int n_in,
                              void* d_out, int out_size, void* d_ws, size_t ws_size,
                              hipStream_t stream) {
    const float* U          = (const float*)d_in[0];
    const float* W          = (const float*)d_in[1];
    const float* beiTa_1    = (const float*)d_in[2];
    const float* beiTa_2    = (const float*)d_in[3];
    const float* B          = (const float*)d_in[4];
    const float* guess_slip = (const float*)d_in[5];
    const float* A_emb      = (const float*)d_in[6];
    const float* gamma_c    = (const float*)d_in[7];
    const float* gamma_e    = (const float*)d_in[8];
    const float* alpha      = (const float*)d_in[9];
    const float* score      = (const float*)d_in[10];
    const float* ukc        = (const float*)d_in[11];
    const float* q_kn       = (const float*)d_in[12];
    const float* d          = (const float*)d_in[13];
    const int*   stu_id     = (const int*)d_in[14];
    const int*   ex_id      = (const int*)d_in[16];
    float* out = (float*)d_out;
    float* ws  = (float*)d_ws;
    float* pA = ws + OFF_PA;
    float* pB = ws + OFF_PB;

    k_fused0<<<dim3(16, 128), 256, 0, stream>>>(B, U, W, beiTa_1, beiTa_2,
                                                guess_slip, A_emb, gamma_c, score,
                                                ukc, q_kn, d, stu_id, ws, pA);
    k_phase<<<dim3(16, 128), 256, 0, stream>>>(ws, out, pA, pB, ukc, W, beiTa_1, 1);
    k_phase<<<dim3(16, 128), 256, 0, stream>>>(ws, out, pB, pA, ukc, W, beiTa_1, 2);
    k_final<<<1, 512, 0, stream>>>(ws, out, pA, ex_id, alpha, gamma_e);
}

// Round 7
// 432.974 us; speedup vs baseline: 1.0704x; 1.0704x over previous
//
#include <hip/hip_runtime.h>
#include <math.h>

#define KK 128
#define EE 4096
#define MM 512
#define CP 32   // max nnz per q_kn row (c<=32 verified: absmax exactly 0 in all prior rounds)

// ws float-offset layout (~72 MB of the 1 GiB ws):
#define OFF_U    0              // u[128] (current state, updated by block0 of phases)
#define OFF_PA   128            // partials A [128][16]
#define OFF_PB   2176           // partials B [128][16]
#define OFF_CNT  4224           // int cnt[E]
#define OFF_IDX  8320           // signed char idx[E][CP]  (row-major, sentinel -1)
#define OFF_IDXT 41088          // signed char idxT[CP][E] (i-major, sentinel -1)
#define OFF_PE   73856          // P01, a2, scv, invd, bz  (5 x E floats)
#define OFF_GW   94336          // gW[k][e] = ukc*W*beiTa_1
#define OFF_HW   618624         // hW[k][e] = ukc*W
#define OFF_BC   1142912        // Bc[k][i][e] compacted B (64 MB)

// Measured A/B ladder (this problem, this harness):
//   r0 gather-compact 6-disp:438.8  r1 stream:447.4  r5 stream+fuse:457.0  r6 +setupfuse:463.5
//   r2/r3 in-kernel grid barriers: +580us (L2 writeback storms across 8 XCDs) - never again.
// Lessons: gather > stream (L2 aggregates ~134MB of distinct lines vs 268MB full);
// fusions must remove work, not add redundant recompute. This round: r0 exactly,
// with compaction merged INTO phase 0 (phase 0 needed those B values anyway).

// K1: blocks 0..15 per-e lists + constants + u0; blocks 16..143 gW/hW. (r0 verbatim)
__global__ __launch_bounds__(256) void k_setup(
    const float* __restrict__ U, const float* __restrict__ W,
    const float* __restrict__ beiTa_1, const float* __restrict__ beiTa_2,
    const float* __restrict__ guess_slip, const float* __restrict__ A_emb,
    const float* __restrict__ gamma_c, const float* __restrict__ score,
    const float* __restrict__ ukc, const float* __restrict__ q_kn,
    const float* __restrict__ d, const int* __restrict__ stu_id,
    float* __restrict__ ws)
{
    int tid = threadIdx.x;
    int blk = blockIdx.x;
    if (blk < 16) {
        int e = blk * 256 + tid;
        int* cnt = (int*)(ws + OFF_CNT);
        signed char* idx  = (signed char*)(ws + OFF_IDX);
        signed char* idxT = (signed char*)(ws + OFF_IDXT);
        float* P01  = ws + OFF_PE;
        float* a2   = P01 + EE;
        float* scv  = a2 + EE;
        float* invd = scv + EE;
        float* bz   = invd + EE;

        // sentinel-fill this e's idx row (-1 bytes), then pack ascending support
        int* ip32 = (int*)(idx + e * CP);
        #pragma unroll
        for (int t = 0; t < CP / 4; t++) ip32[t] = -1;
        const float4* qrow = (const float4*)(q_kn + (size_t)e * KK);
        int c = 0;
        for (int j4 = 0; j4 < KK / 4; j4++) {
            float4 q = qrow[j4];
            int j = j4 * 4;
            if (q.x > 0.5f) { if (c < CP) idx[e*CP+c] = (signed char)j;     c++; }
            if (q.y > 0.5f) { if (c < CP) idx[e*CP+c] = (signed char)(j+1); c++; }
            if (q.z > 0.5f) { if (c < CP) idx[e*CP+c] = (signed char)(j+2); c++; }
            if (q.w > 0.5f) { if (c < CP) idx[e*CP+c] = (signed char)(j+3); c++; }
        }
        c = (c < CP) ? c : CP;
        cnt[e] = c;
        // transposed copy (coalesced over e for each i)
        for (int i = 0; i < CP; i++) idxT[(size_t)i * EE + e] = idx[e * CP + i];

        float id_ = 1.0f / d[e];
        invd[e] = id_;
        float scr = score[e];
        scv[e] = scr;
        P01[e] = A_emb[3*e] * (1.0f - guess_slip[2*e]) +
                 A_emb[3*e+1] * (1.0f - guess_slip[2*e+1]);
        a2[e] = A_emb[3*e+2];
        float zc = 1.0f / (1.0f + __expf(gamma_c[e] * id_ * (scr - 0.5f))) - 0.5f;
        bz[e] = beiTa_2[e] * zc;

        if (blk == 0 && tid < KK) ws[tid] = U[(size_t)stu_id[0] * KK + tid];
    } else {
        float* gW = ws + OFF_GW;
        float* hW = ws + OFF_HW;
        int stride = 128 * 256;
        for (int t = (blk - 16) * 256 + tid; t < KK * EE; t += stride) {
            float uw = ukc[t] * W[t];
            hW[t] = uw;
            gW[t] = uw * beiTa_1[t];
        }
    }
}

// K2: phase 0 with compaction folded in. Thread (e = ec*256+tid, k) gathers its
// c needed values DIRECTLY from B (same scattered pattern and ~134 MB distinct-
// line traffic as r0's k_compact -- L2 aggregates the 64B lines), uses them for
// the phase-0 arithmetic (bit-identical: same values, same expression tree),
// and stores them to Bc[k][i][e] (coalesced over e) for phases 1/2.
__global__ __launch_bounds__(256) void k_phase0(
    const float* __restrict__ B, float* __restrict__ ws, float* __restrict__ pout)
{
    __shared__ float lu[KK];
    __shared__ float sdv[KK];
    __shared__ float wred[4];
    int tid = threadIdx.x;
    int ec = blockIdx.x;   // 0..15
    int k  = blockIdx.y;   // 0..127
    int e  = ec * 256 + tid;

    if (tid < KK) {
        float uv = ws[tid];
        lu[tid] = uv;
        float t = uv - 0.5f;
        sdv[tid] = (fabsf(t) > 0.05f) ? t : 0.0f;
    }
    __syncthreads();

    const int* cnt = (const int*)(ws + OFF_CNT);
    const signed char* idxT = (const signed char*)(ws + OFF_IDXT);
    const float* P01  = ws + OFF_PE;
    const float* a2   = P01 + EE;
    const float* scv  = a2 + EE;
    const float* invd = scv + EE;
    const float* bzv  = invd + EE;
    const float* gW   = ws + OFF_GW;
    const float* hW   = ws + OFF_HW;
    float* Bc = ws + OFF_BC;

    int c = cnt[e];
    const signed char* it = idxT + e;
    const float* Brow = B + ((size_t)k * EE + e) * KK;
    float* BcB = Bc + (size_t)k * CP * EE + e;
    float su = 0.0f, gs = 0.0f;
    for (int i = 0; i < c; i++) {
        int j   = it[(size_t)i * EE];
        float b = Brow[j];                 // scattered gather (L2-aggregated)
        BcB[(size_t)i * EE] = b;           // coalesced store for p1/p2
        su += lu[j];
        gs = fmaf(b, (j != k) ? sdv[j] : 0.0f, gs);   // diag term cancels exactly
    }
    float t0 = scv[e] - su * invd[e];
    float yc = __expf(-t0 * t0);
    float Ic = 1.0f / (1.0f + __expf(P01[e] + a2[e] * yc));
    float Gkc = 1.0f / (1.0f + __expf(gs)) - 1.0f;
    size_t o = (size_t)k * EE + e;
    float v = Ic * (gW[o] * Gkc + hW[o] * bzv[e]);

    #pragma unroll
    for (int m = 1; m < 64; m <<= 1) v += __shfl_xor(v, m);
    if ((tid & 63) == 0) wred[tid >> 6] = v;
    __syncthreads();
    if (tid == 0) pout[k * 16 + ec] = wred[0] + wred[1] + wred[2] + wred[3];
}

// K3: one model iteration (phase 1/2). Block = (e-chunk 256, k). (r0 verbatim)
__global__ __launch_bounds__(256) void k_phase(
    float* __restrict__ ws, float* __restrict__ out,
    const float* __restrict__ pin, float* __restrict__ pout, int phase)
{
    __shared__ float lu[KK];
    __shared__ float sdv[KK];
    __shared__ float red2[KK];
    __shared__ float wred[4];
    int tid = threadIdx.x;
    int ec = blockIdx.x;   // 0..15
    int k  = blockIdx.y;   // 0..127
    int e  = ec * 256 + tid;

    if (tid < KK) {
        float s = 0.0f;
        const float* p = pin + tid * 16;
        #pragma unroll
        for (int t = 0; t < 16; t++) s += p[t];
        float uv = 1.0f / (1.0f + __expf(s));
        lu[tid] = uv;
        float t = uv - 0.5f;
        sdv[tid] = (fabsf(t) > 0.05f) ? t : 0.0f;
    }
    __syncthreads();

    const int* cnt = (const int*)(ws + OFF_CNT);
    const signed char* idxT = (const signed char*)(ws + OFF_IDXT);
    const float* P01  = ws + OFF_PE;
    const float* a2   = P01 + EE;
    const float* scv  = a2 + EE;
    const float* invd = scv + EE;
    const float* bzv  = invd + EE;
    const float* gW   = ws + OFF_GW;
    const float* hW   = ws + OFF_HW;
    const float* Bc   = ws + OFF_BC;

    int c = cnt[e];
    const signed char* it = idxT + e;
    const float* bp = Bc + (size_t)k * CP * EE + e;
    float su = 0.0f, gs = 0.0f;
    for (int i = 0; i < c; i++) {
        int j   = it[(size_t)i * EE];
        float b = bp[(size_t)i * EE];
        su += lu[j];
        gs = fmaf(b, (j != k) ? sdv[j] : 0.0f, gs);   // diag term cancels exactly
    }
    float t0 = scv[e] - su * invd[e];
    float yc = __expf(-t0 * t0);
    float Ic = 1.0f / (1.0f + __expf(P01[e] + a2[e] * yc));
    float Gkc = 1.0f / (1.0f + __expf(gs)) - 1.0f;
    size_t o = (size_t)k * EE + e;
    float v = Ic * (gW[o] * Gkc + hW[o] * bzv[e]);

    #pragma unroll
    for (int m = 1; m < 64; m <<= 1) v += __shfl_xor(v, m);
    if ((tid & 63) == 0) wred[tid >> 6] = v;
    __syncthreads();
    if (tid == 0) pout[k * 16 + ec] = wred[0] + wred[1] + wred[2] + wred[3];

    // bookkeeping: diff norm of previous update, advance ws-u, state_2nd_last
    if (blockIdx.x == 0 && blockIdx.y == 0) {
        if (tid < KK) {
            float dd = lu[tid] - ws[tid];
            red2[tid] = dd * dd;
        }
        __syncthreads();
        for (int s2 = 64; s2 > 0; s2 >>= 1) {
            if (tid < s2) red2[tid] += red2[tid + s2];
            __syncthreads();
        }
        if (tid == 0) out[768 + (phase - 1)] = sqrtf(red2[0]);
        if (tid < KK) {
            ws[tid] = lu[tid];
            if (phase == 2) out[128 + tid] = lu[tid];   // state_2nd_last
        }
    }
}

// K4: final update + diff + state_last + predict (M=512). (r0 verbatim)
__global__ __launch_bounds__(512) void k_final(
    float* __restrict__ ws, float* __restrict__ out, const float* __restrict__ pin,
    const int* __restrict__ ex_id, const float* __restrict__ alpha,
    const float* __restrict__ gamma_e)
{
    __shared__ float un_s[KK];
    __shared__ float red[KK];
    int tid = threadIdx.x;
    if (tid < KK) {
        float s = 0.0f;
        const float* p = pin + tid * 16;
        #pragma unroll
        for (int t = 0; t < 16; t++) s += p[t];
        float un = 1.0f / (1.0f + __expf(s));
        float dd = un - ws[tid];
        red[tid] = dd * dd;
        un_s[tid] = un;
        out[tid] = un;   // state_last
    }
    __syncthreads();
    for (int s2 = 64; s2 > 0; s2 >>= 1) {
        if (tid < s2) red[tid] += red[tid + s2];
        __syncthreads();
    }
    if (tid == 0) out[770] = sqrtf(red[0]);

    const int* cnt = (const int*)(ws + OFF_CNT);
    const signed char* idx = (const signed char*)(ws + OFF_IDX);
    const float* invd = ws + OFF_PE + 3 * EE;
    int e = ex_id[tid];
    int c = cnt[e];
    const signed char* ip = idx + (size_t)e * CP;
    float su = 0.0f;
    for (int i = 0; i < c; i++) su += un_s[ip[i]];
    float Ukse = su * invd[e] - 0.5f;
    out[256 + tid] = 1.0f / (1.0f + __expf(alpha[e] * Ukse + gamma_e[e]));
}

extern "C" void kernel_launch(void* const* d_in, const int* in_sizes, int n_in,
                              void* d_out, int out_size, void* d_ws, size_t ws_size,
                              hipStream_t stream) {
    const float* U          = (const float*)d_in[0];
    const float* W          = (const float*)d_in[1];
    const float* beiTa_1    = (const float*)d_in[2];
    const float* beiTa_2    = (const float*)d_in[3];
    const float* B          = (const float*)d_in[4];
    const float* guess_slip = (const float*)d_in[5];
    const float* A_emb      = (const float*)d_in[6];
    const float* gamma_c    = (const float*)d_in[7];
    const float* gamma_e    = (const float*)d_in[8];
    const float* alpha      = (const float*)d_in[9];
    const float* score      = (const float*)d_in[10];
    const float* ukc        = (const float*)d_in[11];
    const float* q_kn       = (const float*)d_in[12];
    const float* d          = (const float*)d_in[13];
    const int*   stu_id     = (const int*)d_in[14];
    const int*   ex_id      = (const int*)d_in[16];
    float* out = (float*)d_out;
    float* ws  = (float*)d_ws;
    float* pA = ws + OFF_PA;
    float* pB = ws + OFF_PB;

    k_setup<<<144, 256, 0, stream>>>(U, W, beiTa_1, beiTa_2, guess_slip, A_emb,
                                     gamma_c, score, ukc, q_kn, d, stu_id, ws);
    k_phase0<<<dim3(16, 128), 256, 0, stream>>>(B, ws, pA);
    k_phase<<<dim3(16, 128), 256, 0, stream>>>(ws, out, pA, pB, 1);
    k_phase<<<dim3(16, 128), 256, 0, stream>>>(ws, out, pB, pA, 2);
    k_final<<<1, 512, 0, stream>>>(ws, out, pA, ex_id, alpha, gamma_e);
}